// Round 13
// baseline (504.504 us; speedup 1.0000x reference)
//
#include <hip/hip_runtime.h>

// ---------------------------------------------------------------------------
// MHA forward: context = (softmax(mask(QK^T/sqrt(dk))) @ V) @ Wo^T + b
// Outputs: [context (2*2048*1024 f32)] ++ [attention (2*16*2048*2048 f32)]
// B=2 L=2048 DM=1024 H=16 DK=DV=64
// R13: identical to R12 EXCEPT attn_pass2_k launched twice (idempotent) to
// re-attribute its duration post-NT/post-restructure:
// t(pass2) = dur(R13) - dur(R12).
// ---------------------------------------------------------------------------

typedef __attribute__((ext_vector_type(8))) short short8;   // 8 bf16
typedef __attribute__((ext_vector_type(4))) float f32x4;    // 4 f32 acc

#define MFMA_BF16(a,b,c) __builtin_amdgcn_mfma_f32_16x16x32_bf16((a),(b),(c),0,0,0)

__device__ __forceinline__ unsigned short f2bf(float f){   // RNE f32->bf16
  union { float f; unsigned u; } x; x.f = f;
  unsigned r = (x.u + 0x7fffu + ((x.u >> 16) & 1u)) >> 16;
  return (unsigned short)r;
}
__device__ __forceinline__ float bf2f(unsigned short h){
  union { unsigned u; float f; } x; x.u = ((unsigned)h) << 16; return x.f;
}
__device__ __forceinline__ unsigned cvt_pk_bf16(float lo, float hi){
  unsigned r;
  asm("v_cvt_pk_bf16_f32 %0, %1, %2" : "=v"(r) : "v"(lo), "v"(hi));
  return r;   // low16 = bf16(lo), high16 = bf16(hi)
}

typedef __attribute__((address_space(1))) const void gas_void;
typedef __attribute__((address_space(3))) void las_void;
__device__ __forceinline__ void gload16(const void* g, void* l){
  __builtin_amdgcn_global_load_lds((gas_void*)g, (las_void*)l, 16, 0, 0);
}

// ------------------------------------------------- fused prep (1 kernel) ---
__global__ __launch_bounds__(256) void prep_k(
    const float* __restrict__ q, const float* __restrict__ k,
    const float* __restrict__ v, const int* __restrict__ mask,
    const float* __restrict__ wq, const float* __restrict__ wk,
    const float* __restrict__ wv, const float* __restrict__ wo,
    unsigned short* __restrict__ qhi, unsigned short* __restrict__ qlo,
    unsigned short* __restrict__ khi, unsigned short* __restrict__ klo,
    unsigned short* __restrict__ vb,
    unsigned short* __restrict__ wqh, unsigned short* __restrict__ wql,
    unsigned short* __restrict__ wkh, unsigned short* __restrict__ wkl,
    unsigned short* __restrict__ wvb, unsigned short* __restrict__ wob_,
    unsigned long long* __restrict__ bits){
  const int blk = blockIdx.x;
  if (blk >= 16384){                         // ---- mask pack ----
    int mb = blk - 16384;
    int base = mb*1024 + (threadIdx.x >> 6)*256;
    int lane = threadIdx.x & 63;
#pragma unroll
    for (int j=0;j<4;j++){
      unsigned long long w = __ballot(mask[base + j*64 + lane] != 0);
      if (lane == 0) bits[(base >> 6) + j] = w;
    }
    return;
  }
  const float* src; unsigned short *hi, *lo; bool split; int i;
  if (blk < 12288){
    i = (blk & 4095)*256 + threadIdx.x;
    if (blk < 4096){ src=q; hi=qhi; lo=qlo; split=true; }
    else if (blk < 8192){ src=k; hi=khi; lo=klo; split=true; }
    else { src=v; hi=vb; lo=nullptr; split=false; }
  } else {
    i = (blk & 1023)*256 + threadIdx.x;
    int seg = (blk - 12288) >> 10;
    if (seg==0){ src=wq; hi=wqh; lo=wql; split=true; }
    else if (seg==1){ src=wk; hi=wkh; lo=wkl; split=true; }
    else if (seg==2){ src=wv; hi=wvb; lo=nullptr; split=false; }
    else { src=wo; hi=wob_; lo=nullptr; split=false; }
  }
  float4 f = reinterpret_cast<const float4*>(src)[i];
  ushort4 oh;
  oh.x=f2bf(f.x); oh.y=f2bf(f.y); oh.z=f2bf(f.z); oh.w=f2bf(f.w);
  reinterpret_cast<ushort4*>(hi)[i] = oh;
  if (split){
    ushort4 ol;
    ol.x=f2bf(f.x - bf2f(oh.x)); ol.y=f2bf(f.y - bf2f(oh.y));
    ol.z=f2bf(f.z - bf2f(oh.z)); ol.w=f2bf(f.w - bf2f(oh.w));
    reinterpret_cast<ushort4*>(lo)[i] = ol;
  }
}

// --------------------------------------------- fused Q/K/V projections -----
// Hi/lo split as K-concat GEMM: A' = [Ah|Al|Ah], W' = [Wh|Wh|Wl], K' = 3072.
__global__ __launch_bounds__(256,3) void proj_qkv_k(
    const unsigned short* __restrict__ qhi, const unsigned short* __restrict__ qlo,
    const unsigned short* __restrict__ khi, const unsigned short* __restrict__ klo,
    const unsigned short* __restrict__ vb,
    const unsigned short* __restrict__ wqh, const unsigned short* __restrict__ wql,
    const unsigned short* __restrict__ wkh, const unsigned short* __restrict__ wkl,
    const unsigned short* __restrict__ wvb,
    unsigned short* __restrict__ Qp, unsigned short* __restrict__ Kp,
    unsigned short* __restrict__ Vt){
  __shared__ __align__(16) char SA[2][8192];
  __shared__ __align__(16) char SB[2][8192];
  const int z = blockIdx.z;
  const unsigned short *A0, *A1, *W0, *W2;
  int nkt;
  if (z==0){ A0=qhi; A1=qlo; W0=wqh; W2=wql; nkt=96; }
  else if (z==1){ A0=khi; A1=klo; W0=wkh; W2=wkl; nkt=96; }
  else { A0=vb; A1=vb; W0=wvb; W2=wvb; nkt=32; }
  const int tid = threadIdx.x;
  const int wave = tid >> 6, lane = tid & 63;
  const int lr = lane & 15, lg = lane >> 4;
  const int m0 = blockIdx.y * 128, n0 = blockIdx.x * 128;
  const int wr = wave >> 1, wc = wave & 1;
  const f32x4 fz = {0.f,0.f,0.f,0.f};

  f32x4 acc[4][4];
#pragma unroll
  for (int i=0;i<4;i++)
#pragma unroll
    for (int j=0;j<4;j++) acc[i][j] = fz;

  auto stage = [&](int kt, int bu){
    int seg = kt >> 5;
    int kof = (kt & 31)*32 + (tid&3)*8;
    const unsigned short* A_ = (seg==1) ? A1 : A0;
    const unsigned short* W_ = (seg==2) ? W2 : W0;
#pragma unroll
    for (int i=0;i<2;i++){
      int row = i*64 + (tid>>2);
      int dof = i*4096 + wave*1024;
      gload16(A_ + (size_t)(m0+row)*1024 + kof, &SA[bu][dof]);
      gload16(W_ + (size_t)(n0+row)*1024 + kof, &SB[bu][dof]);
    }
  };
  stage(0,0);
  int buf = 0;
  for (int kt=0; kt<nkt; ++kt){
    __syncthreads();
    if (kt+1 < nkt) stage(kt+1, buf^1);
    short8 af[4], bf[4];
#pragma unroll
    for (int i=0;i<4;i++) af[i] = *(const short8*)(&SA[buf][(wr*64+i*16+lr)*64 + lg*16]);
#pragma unroll
    for (int j=0;j<4;j++) bf[j] = *(const short8*)(&SB[buf][(wc*64+j*16+lr)*64 + lg*16]);
#pragma unroll
    for (int i=0;i<4;i++)
#pragma unroll
      for (int j=0;j<4;j++)
        acc[i][j] = MFMA_BF16(af[i], bf[j], acc[i][j]);
    buf ^= 1;
  }

  if (z < 2){
    unsigned short* out = (z==0) ? Qp : Kp;
#pragma unroll
    for (int i=0;i<4;i++)
#pragma unroll
      for (int j=0;j<4;j++)
#pragma unroll
        for (int r=0;r<4;r++){
          int m = m0 + wr*64 + i*16 + lg*4 + r;
          int n = n0 + wc*64 + j*16 + lr;
          out[(size_t)m*1024 + n] = f2bf(acc[i][j][r]);
        }
  } else {
#pragma unroll
    for (int i=0;i<4;i++)
#pragma unroll
      for (int j=0;j<4;j++){
        int m = m0 + wr*64 + i*16 + lg*4;
        int n = n0 + wc*64 + j*16 + lr;
        int b = m >> 11, lrow = m & 2047;
        int h = n >> 6,  dv = n & 63;
        ushort4 o;
        o.x = f2bf(acc[i][j][0]); o.y = f2bf(acc[i][j][1]);
        o.z = f2bf(acc[i][j][2]); o.w = f2bf(acc[i][j][3]);
        *reinterpret_cast<ushort4*>(Vt + ((size_t)((b*16+h)*64+dv))*2048 + lrow) = o;
      }
  }
}

// ----------------------------------------------------- attention pass 1 ----
// Swapped QK^T: s2 = mfma(K,Q) -> lane owns q=lr, k=bj*16+lg*4+r.
__global__ __launch_bounds__(256,3) void attn_pass1_k(
    const unsigned short* __restrict__ Qp, const unsigned short* __restrict__ Kp,
    const unsigned long long* __restrict__ mbits, float* __restrict__ linv){
  __shared__ __align__(16) char Ks[2][16384];
  const int tid = threadIdx.x;
  const int wave = tid >> 6, lane = tid & 63;
  const int lr = lane & 15, lg = lane >> 4;
  const int flat = blockIdx.x;                    // 512 blocks
  const int wg = ((flat & 7) << 6) + (flat >> 3); // XCD-contiguous
  const int bh = wg >> 4, b = bh >> 4, h = bh & 15;
  const int qbase = (wg & 15)*128 + wave*32;
  const f32x4 fz = {0.f,0.f,0.f,0.f};

  short8 qf[2][2];
#pragma unroll
  for (int ai=0;ai<2;ai++)
#pragma unroll
    for (int ks=0;ks<2;ks++)
      qf[ai][ks] = *(const short8*)(Qp + (size_t)(b*2048 + qbase + ai*16 + lr)*1024
                                    + h*64 + ks*32 + lg*8);
  float psum[2] = {0.f, 0.f};

  auto stageK = [&](int t, int bu){
#pragma unroll
    for (int i=0;i<4;i++){
      int byte = i*4096 + tid*16;
      int row = byte >> 7;
      int ch  = (byte >> 4) & 7;
      gload16(Kp + (size_t)(b*2048 + t*128 + row)*1024 + h*64 + ((ch ^ (row&7))*8),
              &Ks[bu][i*4096 + wave*1024]);
    }
  };
  stageK(0,0);
  int buf = 0;
  for (int t=0; t<16; ++t){
    __syncthreads();
    if (t+1 < 16) stageK(t+1, buf^1);
    f32x4 s2[2][8];
#pragma unroll
    for (int ai=0;ai<2;ai++)
#pragma unroll
      for (int bj=0;bj<8;bj++) s2[ai][bj] = fz;
#pragma unroll
    for (int ks=0;ks<2;ks++){
      short8 kf[8];
#pragma unroll
      for (int bj=0;bj<8;bj++){
        int row = bj*16 + lr;
        kf[bj] = *(const short8*)(&Ks[buf][row*128 + (((ks*4+lg) ^ (row&7))*16)]);
      }
#pragma unroll
      for (int ai=0;ai<2;ai++)
#pragma unroll
        for (int bj=0;bj<8;bj++)
          s2[ai][bj] = MFMA_BF16(kf[bj], qf[ai][ks], s2[ai][bj]);  // swapped
    }
#pragma unroll
    for (int ai=0;ai<2;ai++){
      int qrow = qbase + ai*16 + lr;
      ulonglong2 mw = *reinterpret_cast<const ulonglong2*>(
          mbits + (((size_t)(b*2048 + qrow)) << 5) + t*2);
      unsigned long long wx = mw.x >> (lg*4);
      unsigned long long wy = mw.y >> (lg*4);
      float a0 = 0.f;
#pragma unroll
      for (int bj=0;bj<8;bj++){
        unsigned ub = (unsigned)(((bj<4) ? wx : wy) >> ((bj&3)*16));
#pragma unroll
        for (int r=0;r<4;r++){
          float e = __expf(s2[ai][bj][r]*0.125f);
          a0 += (ub & (1u<<r)) ? e : 0.f;
        }
      }
      psum[ai] += a0;
    }
    buf ^= 1;
  }
#pragma unroll
  for (int ai=0;ai<2;ai++){
    float v = psum[ai];
    v += __shfl_xor(v, 16, 64);
    v += __shfl_xor(v, 32, 64);
    if (lg == 0)
      linv[(size_t)bh*2048 + qbase + ai*16 + lr] = 1.f / v;
  }
}

// ----------------------------------------------------- attention pass 2 ----
// Swapped QK^T; QBLK=64, KVBLK=64; NT float4 attention stores; mask word
// prefetched one tile ahead; Ps stride 64 + XOR swizzle; 4 blocks/CU.
__global__ __launch_bounds__(256,4) void attn_pass2_k(
    const unsigned short* __restrict__ Qp, const unsigned short* __restrict__ Kp,
    const unsigned short* __restrict__ Vt, const unsigned long long* __restrict__ mbits,
    const float* __restrict__ linv, float* __restrict__ attn,
    unsigned short* __restrict__ ctx){
  __shared__ __align__(16) char Ks[2][8192];          // 64 k x 64 dk
  __shared__ __align__(16) char Vs[2][8192];          // 64 dv x 64 k
  __shared__ __align__(16) unsigned short Ps[64*64];  // stride 64, XOR-swizzled
  const int tid = threadIdx.x;
  const int wave = tid >> 6, lane = tid & 63;
  const int lr = lane & 15, lg = lane >> 4;
  const int flat = blockIdx.x;                        // 1024 blocks
  const int wg = ((flat & 7) << 7) + (flat >> 3);     // XCD-contiguous
  const int bh = wg >> 5, b = bh >> 4, h = bh & 15;
  const int qbase = (wg & 31)*64 + wave*16;
  const f32x4 fz = {0.f,0.f,0.f,0.f};

  short8 qf[2];
#pragma unroll
  for (int ks=0;ks<2;ks++)
    qf[ks] = *(const short8*)(Qp + (size_t)(b*2048 + qbase + lr)*1024
                              + h*64 + ks*32 + lg*8);
  const int qrow = qbase + lr;
  const float li = linv[(size_t)bh*2048 + qrow];
  const unsigned long long* mrow = mbits + (((size_t)(b*2048 + qrow)) << 5);

  f32x4 oacc[4];
#pragma unroll
  for (int bj=0;bj<4;bj++) oacc[bj] = fz;

  auto stageK = [&](int t, int bu){
#pragma unroll
    for (int i=0;i<2;i++){
      int byte = i*4096 + tid*16;
      int row = byte >> 7;
      int ch  = (byte >> 4) & 7;
      gload16(Kp + (size_t)(b*2048 + t*64 + row)*1024 + h*64 + ((ch ^ (row&7))*8),
              &Ks[bu][i*4096 + wave*1024]);
    }
  };
  auto stageV = [&](int t, int bu){
#pragma unroll
    for (int i=0;i<2;i++){
      int byte = i*4096 + tid*16;
      int row = byte >> 7;
      int ch  = (byte >> 4) & 7;
      gload16(Vt + (size_t)(bh*64 + row)*2048 + t*64 + ((ch ^ (row&7))*8),
              &Vs[bu][i*4096 + wave*1024]);
    }
  };
  auto wload = [&](int t) -> unsigned long long {
    unsigned long long wv;
    const unsigned long long* ma = mrow + t;
    asm volatile("global_load_dwordx2 %0, %1, off" : "=v"(wv) : "v"(ma));
    return wv;
  };

  // prologue: stage tile 0 + mask word 0, full drain, align waves
  stageK(0,0); stageV(0,0);
  unsigned long long w_cur = wload(0), w_nxt = 0;
  asm volatile("s_waitcnt vmcnt(0)" ::: "memory");
  __builtin_amdgcn_s_barrier();

  char* psb = (char*)Ps;
  const int prow = (wave*16 + lr);                 // Ps row for this lane
  const int pswz = (lr & 7) << 4;                  // XOR byte swizzle
  int buf = 0;
  for (int t=0; t<32; ++t){
    // issue next tile's gloads + mask word FIRST (all older than stores)
    if (t+1 < 32){ stageK(t+1, buf^1); stageV(t+1, buf^1); w_nxt = wload(t+1); }
    __builtin_amdgcn_sched_barrier(0);

    f32x4 s2[4];
#pragma unroll
    for (int bj=0;bj<4;bj++) s2[bj] = fz;
#pragma unroll
    for (int ks=0;ks<2;ks++){
      short8 kf[4];
#pragma unroll
      for (int bj=0;bj<4;bj++){
        int row = bj*16 + lr;
        kf[bj] = *(const short8*)(&Ks[buf][row*128 + (((ks*4+lg) ^ (row&7))*16)]);
      }
#pragma unroll
      for (int bj=0;bj<4;bj++)
        s2[bj] = MFMA_BF16(kf[bj], qf[ks], s2[bj]);   // swapped
    }
    // softmax + NT attention stores + Ps writes (w_cur completed last tile)
    unsigned long long w2 = w_cur >> (lg*4);
    float* arow = attn + ((size_t)bh*2048 + qrow)*2048 + t*64 + lg*4;
#pragma unroll
    for (int bj=0;bj<4;bj++){
      unsigned ub = (unsigned)(w2 >> (bj*16));
      f32x4 po;
#pragma unroll
      for (int r=0;r<4;r++){
        float e = __expf(s2[bj][r]*0.125f);
        po[r] = (ub & (1u<<r)) ? e*li : 0.f;
      }
      __builtin_nontemporal_store(po, reinterpret_cast<f32x4*>(arow + bj*16));
      uint2 pk;
      pk.x = cvt_pk_bf16(po[0], po[1]);
      pk.y = cvt_pk_bf16(po[2], po[3]);
      *reinterpret_cast<uint2*>(psb + prow*128 + (((bj*32 + lg*8) ^ pswz))) = pk;
    }
    // PV: O(16q x 64dv) += P(16q x 64k) @ V(64k x 64dv)
#pragma unroll
    for (int ks=0;ks<2;ks++){
      short8 pa = *(const short8*)(psb + prow*128 + (((ks*64 + lg*16) ^ pswz)));
      short8 vf[4];
#pragma unroll
      for (int bj=0;bj<4;bj++){
        int row = bj*16 + lr;
        vf[bj] = *(const short8*)(&Vs[buf][row*128 + (((ks*4+lg) ^ (row&7))*16)]);
      }
#pragma unroll
      for (int bj=0;bj<4;bj++)
        oacc[bj] = MFMA_BF16(pa, vf[bj], oacc[bj]);
    }
    if (t+1 < 32){
      __builtin_amdgcn_sched_barrier(0);
      asm volatile("s_waitcnt vmcnt(4)" ::: "memory");
      asm volatile("s_waitcnt lgkmcnt(0)" ::: "memory");
      __builtin_amdgcn_s_barrier();
    }
    w_cur = w_nxt;
    buf ^= 1;
  }
  // ctx write: q = qbase + lg*4 + r, dv = bj*16 + lr
#pragma unroll
  for (int bj=0;bj<4;bj++)
#pragma unroll
    for (int r=0;r<4;r++){
      int qr2 = qbase + lg*4 + r;
      int dv = bj*16 + lr;
      ctx[(size_t)(b*2048 + qr2)*1024 + h*64 + dv] = f2bf(oacc[bj][r]);
    }
}

// --------------------------------------------------- out-proj (BM=64) ------
__global__ __launch_bounds__(256,4) void gemm_out_k(const unsigned short* __restrict__ A,
    const unsigned short* __restrict__ W, float* __restrict__ out,
    const float* __restrict__ bias){
  __shared__ __align__(16) char As[2][4096];
  __shared__ __align__(16) char Bs[2][8192];
  const int tid = threadIdx.x;
  const int wave = tid >> 6, lane = tid & 63;
  const int lr = lane & 15, lg = lane >> 4;
  const int m0 = blockIdx.y * 64, n0 = blockIdx.x * 128;
  const int wr = wave >> 1, wc = wave & 1;
  const f32x4 fz = {0.f,0.f,0.f,0.f};

  f32x4 acc[2][4];
#pragma unroll
  for (int i=0;i<2;i++)
#pragma unroll
    for (int j=0;j<4;j++) acc[i][j] = fz;

  auto stage = [&](int kt, int bu){
    int kof = kt*32 + (tid&3)*8;
    gload16(A + (size_t)(m0 + (tid>>2))*1024 + kof, &As[bu][wave*1024]);
#pragma unroll
    for (int i=0;i<2;i++){
      int row = i*64 + (tid>>2);
      gload16(W + (size_t)(n0+row)*1024 + kof, &Bs[bu][i*4096 + wave*1024]);
    }
  };
  stage(0,0);
  int buf = 0;
  for (int kt=0; kt<32; ++kt){
    __syncthreads();
    if (kt+1 < 32) stage(kt+1, buf^1);
    short8 af[2], bf[4];
#pragma unroll
    for (int i=0;i<2;i++) af[i] = *(const short8*)(&As[buf][(wr*32+i*16+lr)*64 + lg*16]);
#pragma unroll
    for (int j=0;j<4;j++) bf[j] = *(const short8*)(&Bs[buf][(wc*64+j*16+lr)*64 + lg*16]);
#pragma unroll
    for (int i=0;i<2;i++)
#pragma unroll
      for (int j=0;j<4;j++)
        acc[i][j] = MFMA_BF16(af[i], bf[j], acc[i][j]);
    buf ^= 1;
  }
#pragma unroll
  for (int i=0;i<2;i++)
#pragma unroll
    for (int j=0;j<4;j++){
      int n = n0 + wc*64 + j*16 + lr;
      float bv = bias[n];
#pragma unroll
      for (int r=0;r<4;r++){
        int m = m0 + wr*32 + i*16 + lg*4 + r;
        out[(size_t)m*1024 + n] = acc[i][j][r] + bv;
      }
    }
}

// ------------------------------------------------------------------ host ---
extern "C" void kernel_launch(void* const* d_in, const int* in_sizes, int n_in,
                              void* d_out, int out_size, void* d_ws, size_t ws_size,
                              hipStream_t stream){
  (void)in_sizes; (void)n_in; (void)out_size;
  const float* q   = (const float*)d_in[0];
  const float* k   = (const float*)d_in[1];
  const float* v   = (const float*)d_in[2];
  const int*  mask = (const int*)d_in[3];
  const float* wq  = (const float*)d_in[4];
  const float* wk  = (const float*)d_in[5];
  const float* wv  = (const float*)d_in[6];
  const float* wo  = (const float*)d_in[7];
  const float* wob = (const float*)d_in[8];

  char* ws = (char*)d_ws;
  const size_t MB = 1ull << 20;
  unsigned short* qhi = (unsigned short*)(ws +  0*MB);
  unsigned short* qlo = (unsigned short*)(ws +  8*MB);
  unsigned short* khi = (unsigned short*)(ws + 16*MB);
  unsigned short* klo = (unsigned short*)(ws + 24*MB);
  unsigned short* vb  = (unsigned short*)(ws + 32*MB);
  unsigned short* wqh = (unsigned short*)(ws + 40*MB);
  unsigned short* wql = (unsigned short*)(ws + 42*MB);
  unsigned short* wkh = (unsigned short*)(ws + 44*MB);
  unsigned short* wkl = (unsigned short*)(ws + 46*MB);
  unsigned short* wvb = (unsigned short*)(ws + 48*MB);
  unsigned short* wob_= (unsigned short*)(ws + 50*MB);   // 2 MB: [50,52)
  unsigned short* Qp  = (unsigned short*)(ws + 52*MB);
  unsigned short* Kp  = (unsigned short*)(ws + 60*MB);
  unsigned short* Vt  = (unsigned short*)(ws + 68*MB);
  unsigned short* Ctx = (unsigned short*)(ws + 76*MB);
  unsigned long long* mbits = (unsigned long long*)(ws + 84*MB);
  // lin (256 KB) reuses the qhi region: qhi is dead after proj_qkv_k.
  float*          lin = (float*)(ws + 0*MB);
  if (ws_size < 85*MB) return;   // need 85 MB scratch

  float* ctx_out  = (float*)d_out;
  float* attn_out = ctx_out + (size_t)2*2048*1024;

  prep_k<<<24576,256,0,stream>>>(q,k,v,mask,wq,wk,wv,wo,
                                 qhi,qlo,khi,klo,vb,
                                 wqh,wql,wkh,wkl,wvb,wob_, mbits);

  proj_qkv_k<<<dim3(8,32,3),256,0,stream>>>(qhi,qlo,khi,klo,vb,
                                            wqh,wql,wkh,wkl,wvb, Qp,Kp,Vt);

  attn_pass1_k<<<512,256,0,stream>>>(Qp, Kp, mbits, lin);
  // MEASUREMENT: pass2 launched twice (idempotent — writes the same attn/ctx
  // values both times). t(pass2) = dur(R13) - dur(R12).
  attn_pass2_k<<<1024,256,0,stream>>>(Qp, Kp, Vt, mbits, lin,
                                      attn_out, Ctx);
  attn_pass2_k<<<1024,256,0,stream>>>(Qp, Kp, Vt, mbits, lin,
                                      attn_out, Ctx);

  gemm_out_k<<<dim3(8,64),256,0,stream>>>(Ctx, wob_, ctx_out, wob);
}

// Round 14
// 295.785 us; speedup vs baseline: 1.7056x; 1.7056x over previous
//
#include <hip/hip_runtime.h>

// ---------------------------------------------------------------------------
// MHA forward: context = (softmax(mask(QK^T/sqrt(dk))) @ V) @ Wo^T + b
// Outputs: [context (2*2048*1024 f32)] ++ [attention (2*16*2048*2048 f32)]
// B=2 L=2048 DM=1024 H=16 DK=DV=64
// R14: pass2 attention store = FULL-LINE NT stores from Ps readback:
// 4 rows x 256B contiguous per store instruction (no 64B partial-line NT
// write amplification). Attention values bf16-rounded (validated in R4).
// ---------------------------------------------------------------------------

typedef __attribute__((ext_vector_type(8))) short short8;   // 8 bf16
typedef __attribute__((ext_vector_type(4))) float f32x4;    // 4 f32 acc

#define MFMA_BF16(a,b,c) __builtin_amdgcn_mfma_f32_16x16x32_bf16((a),(b),(c),0,0,0)

__device__ __forceinline__ unsigned short f2bf(float f){   // RNE f32->bf16
  union { float f; unsigned u; } x; x.f = f;
  unsigned r = (x.u + 0x7fffu + ((x.u >> 16) & 1u)) >> 16;
  return (unsigned short)r;
}
__device__ __forceinline__ float bf2f(unsigned short h){
  union { unsigned u; float f; } x; x.u = ((unsigned)h) << 16; return x.f;
}
__device__ __forceinline__ unsigned cvt_pk_bf16(float lo, float hi){
  unsigned r;
  asm("v_cvt_pk_bf16_f32 %0, %1, %2" : "=v"(r) : "v"(lo), "v"(hi));
  return r;   // low16 = bf16(lo), high16 = bf16(hi)
}

typedef __attribute__((address_space(1))) const void gas_void;
typedef __attribute__((address_space(3))) void las_void;
__device__ __forceinline__ void gload16(const void* g, void* l){
  __builtin_amdgcn_global_load_lds((gas_void*)g, (las_void*)l, 16, 0, 0);
}

// ------------------------------------------------- fused prep (1 kernel) ---
__global__ __launch_bounds__(256) void prep_k(
    const float* __restrict__ q, const float* __restrict__ k,
    const float* __restrict__ v, const int* __restrict__ mask,
    const float* __restrict__ wq, const float* __restrict__ wk,
    const float* __restrict__ wv, const float* __restrict__ wo,
    unsigned short* __restrict__ qhi, unsigned short* __restrict__ qlo,
    unsigned short* __restrict__ khi, unsigned short* __restrict__ klo,
    unsigned short* __restrict__ vb,
    unsigned short* __restrict__ wqh, unsigned short* __restrict__ wql,
    unsigned short* __restrict__ wkh, unsigned short* __restrict__ wkl,
    unsigned short* __restrict__ wvb, unsigned short* __restrict__ wob_,
    unsigned long long* __restrict__ bits){
  const int blk = blockIdx.x;
  if (blk >= 16384){                         // ---- mask pack ----
    int mb = blk - 16384;
    int base = mb*1024 + (threadIdx.x >> 6)*256;
    int lane = threadIdx.x & 63;
#pragma unroll
    for (int j=0;j<4;j++){
      unsigned long long w = __ballot(mask[base + j*64 + lane] != 0);
      if (lane == 0) bits[(base >> 6) + j] = w;
    }
    return;
  }
  const float* src; unsigned short *hi, *lo; bool split; int i;
  if (blk < 12288){
    i = (blk & 4095)*256 + threadIdx.x;
    if (blk < 4096){ src=q; hi=qhi; lo=qlo; split=true; }
    else if (blk < 8192){ src=k; hi=khi; lo=klo; split=true; }
    else { src=v; hi=vb; lo=nullptr; split=false; }
  } else {
    i = (blk & 1023)*256 + threadIdx.x;
    int seg = (blk - 12288) >> 10;
    if (seg==0){ src=wq; hi=wqh; lo=wql; split=true; }
    else if (seg==1){ src=wk; hi=wkh; lo=wkl; split=true; }
    else if (seg==2){ src=wv; hi=wvb; lo=nullptr; split=false; }
    else { src=wo; hi=wob_; lo=nullptr; split=false; }
  }
  float4 f = reinterpret_cast<const float4*>(src)[i];
  ushort4 oh;
  oh.x=f2bf(f.x); oh.y=f2bf(f.y); oh.z=f2bf(f.z); oh.w=f2bf(f.w);
  reinterpret_cast<ushort4*>(hi)[i] = oh;
  if (split){
    ushort4 ol;
    ol.x=f2bf(f.x - bf2f(oh.x)); ol.y=f2bf(f.y - bf2f(oh.y));
    ol.z=f2bf(f.z - bf2f(oh.z)); ol.w=f2bf(f.w - bf2f(oh.w));
    reinterpret_cast<ushort4*>(lo)[i] = ol;
  }
}

// --------------------------------------------- fused Q/K/V projections -----
// Hi/lo split as K-concat GEMM: A' = [Ah|Al|Ah], W' = [Wh|Wh|Wl], K' = 3072.
__global__ __launch_bounds__(256,3) void proj_qkv_k(
    const unsigned short* __restrict__ qhi, const unsigned short* __restrict__ qlo,
    const unsigned short* __restrict__ khi, const unsigned short* __restrict__ klo,
    const unsigned short* __restrict__ vb,
    const unsigned short* __restrict__ wqh, const unsigned short* __restrict__ wql,
    const unsigned short* __restrict__ wkh, const unsigned short* __restrict__ wkl,
    const unsigned short* __restrict__ wvb,
    unsigned short* __restrict__ Qp, unsigned short* __restrict__ Kp,
    unsigned short* __restrict__ Vt){
  __shared__ __align__(16) char SA[2][8192];
  __shared__ __align__(16) char SB[2][8192];
  const int z = blockIdx.z;
  const unsigned short *A0, *A1, *W0, *W2;
  int nkt;
  if (z==0){ A0=qhi; A1=qlo; W0=wqh; W2=wql; nkt=96; }
  else if (z==1){ A0=khi; A1=klo; W0=wkh; W2=wkl; nkt=96; }
  else { A0=vb; A1=vb; W0=wvb; W2=wvb; nkt=32; }
  const int tid = threadIdx.x;
  const int wave = tid >> 6, lane = tid & 63;
  const int lr = lane & 15, lg = lane >> 4;
  const int m0 = blockIdx.y * 128, n0 = blockIdx.x * 128;
  const int wr = wave >> 1, wc = wave & 1;
  const f32x4 fz = {0.f,0.f,0.f,0.f};

  f32x4 acc[4][4];
#pragma unroll
  for (int i=0;i<4;i++)
#pragma unroll
    for (int j=0;j<4;j++) acc[i][j] = fz;

  auto stage = [&](int kt, int bu){
    int seg = kt >> 5;
    int kof = (kt & 31)*32 + (tid&3)*8;
    const unsigned short* A_ = (seg==1) ? A1 : A0;
    const unsigned short* W_ = (seg==2) ? W2 : W0;
#pragma unroll
    for (int i=0;i<2;i++){
      int row = i*64 + (tid>>2);
      int dof = i*4096 + wave*1024;
      gload16(A_ + (size_t)(m0+row)*1024 + kof, &SA[bu][dof]);
      gload16(W_ + (size_t)(n0+row)*1024 + kof, &SB[bu][dof]);
    }
  };
  stage(0,0);
  int buf = 0;
  for (int kt=0; kt<nkt; ++kt){
    __syncthreads();
    if (kt+1 < nkt) stage(kt+1, buf^1);
    short8 af[4], bf[4];
#pragma unroll
    for (int i=0;i<4;i++) af[i] = *(const short8*)(&SA[buf][(wr*64+i*16+lr)*64 + lg*16]);
#pragma unroll
    for (int j=0;j<4;j++) bf[j] = *(const short8*)(&SB[buf][(wc*64+j*16+lr)*64 + lg*16]);
#pragma unroll
    for (int i=0;i<4;i++)
#pragma unroll
      for (int j=0;j<4;j++)
        acc[i][j] = MFMA_BF16(af[i], bf[j], acc[i][j]);
    buf ^= 1;
  }

  if (z < 2){
    unsigned short* out = (z==0) ? Qp : Kp;
#pragma unroll
    for (int i=0;i<4;i++)
#pragma unroll
      for (int j=0;j<4;j++)
#pragma unroll
        for (int r=0;r<4;r++){
          int m = m0 + wr*64 + i*16 + lg*4 + r;
          int n = n0 + wc*64 + j*16 + lr;
          out[(size_t)m*1024 + n] = f2bf(acc[i][j][r]);
        }
  } else {
#pragma unroll
    for (int i=0;i<4;i++)
#pragma unroll
      for (int j=0;j<4;j++){
        int m = m0 + wr*64 + i*16 + lg*4;
        int n = n0 + wc*64 + j*16 + lr;
        int b = m >> 11, lrow = m & 2047;
        int h = n >> 6,  dv = n & 63;
        ushort4 o;
        o.x = f2bf(acc[i][j][0]); o.y = f2bf(acc[i][j][1]);
        o.z = f2bf(acc[i][j][2]); o.w = f2bf(acc[i][j][3]);
        *reinterpret_cast<ushort4*>(Vt + ((size_t)((b*16+h)*64+dv))*2048 + lrow) = o;
      }
  }
}

// ----------------------------------------------------- attention pass 1 ----
// Swapped QK^T: s2 = mfma(K,Q) -> lane owns q=lr, k=bj*16+lg*4+r.
__global__ __launch_bounds__(256,3) void attn_pass1_k(
    const unsigned short* __restrict__ Qp, const unsigned short* __restrict__ Kp,
    const unsigned long long* __restrict__ mbits, float* __restrict__ linv){
  __shared__ __align__(16) char Ks[2][16384];
  const int tid = threadIdx.x;
  const int wave = tid >> 6, lane = tid & 63;
  const int lr = lane & 15, lg = lane >> 4;
  const int flat = blockIdx.x;                    // 512 blocks
  const int wg = ((flat & 7) << 6) + (flat >> 3); // XCD-contiguous
  const int bh = wg >> 4, b = bh >> 4, h = bh & 15;
  const int qbase = (wg & 15)*128 + wave*32;
  const f32x4 fz = {0.f,0.f,0.f,0.f};

  short8 qf[2][2];
#pragma unroll
  for (int ai=0;ai<2;ai++)
#pragma unroll
    for (int ks=0;ks<2;ks++)
      qf[ai][ks] = *(const short8*)(Qp + (size_t)(b*2048 + qbase + ai*16 + lr)*1024
                                    + h*64 + ks*32 + lg*8);
  float psum[2] = {0.f, 0.f};

  auto stageK = [&](int t, int bu){
#pragma unroll
    for (int i=0;i<4;i++){
      int byte = i*4096 + tid*16;
      int row = byte >> 7;
      int ch  = (byte >> 4) & 7;
      gload16(Kp + (size_t)(b*2048 + t*128 + row)*1024 + h*64 + ((ch ^ (row&7))*8),
              &Ks[bu][i*4096 + wave*1024]);
    }
  };
  stageK(0,0);
  int buf = 0;
  for (int t=0; t<16; ++t){
    __syncthreads();
    if (t+1 < 16) stageK(t+1, buf^1);
    f32x4 s2[2][8];
#pragma unroll
    for (int ai=0;ai<2;ai++)
#pragma unroll
      for (int bj=0;bj<8;bj++) s2[ai][bj] = fz;
#pragma unroll
    for (int ks=0;ks<2;ks++){
      short8 kf[8];
#pragma unroll
      for (int bj=0;bj<8;bj++){
        int row = bj*16 + lr;
        kf[bj] = *(const short8*)(&Ks[buf][row*128 + (((ks*4+lg) ^ (row&7))*16)]);
      }
#pragma unroll
      for (int ai=0;ai<2;ai++)
#pragma unroll
        for (int bj=0;bj<8;bj++)
          s2[ai][bj] = MFMA_BF16(kf[bj], qf[ai][ks], s2[ai][bj]);  // swapped
    }
#pragma unroll
    for (int ai=0;ai<2;ai++){
      int qrow = qbase + ai*16 + lr;
      ulonglong2 mw = *reinterpret_cast<const ulonglong2*>(
          mbits + (((size_t)(b*2048 + qrow)) << 5) + t*2);
      unsigned long long wx = mw.x >> (lg*4);
      unsigned long long wy = mw.y >> (lg*4);
      float a0 = 0.f;
#pragma unroll
      for (int bj=0;bj<8;bj++){
        unsigned ub = (unsigned)(((bj<4) ? wx : wy) >> ((bj&3)*16));
#pragma unroll
        for (int r=0;r<4;r++){
          float e = __expf(s2[ai][bj][r]*0.125f);
          a0 += (ub & (1u<<r)) ? e : 0.f;
        }
      }
      psum[ai] += a0;
    }
    buf ^= 1;
  }
#pragma unroll
  for (int ai=0;ai<2;ai++){
    float v = psum[ai];
    v += __shfl_xor(v, 16, 64);
    v += __shfl_xor(v, 32, 64);
    if (lg == 0)
      linv[(size_t)bh*2048 + qbase + ai*16 + lr] = 1.f / v;
  }
}

// ----------------------------------------------------- attention pass 2 ----
// Swapped QK^T; QBLK=64, KVBLK=64. Softmax -> Ps (bf16, XOR-swizzled).
// Attention stored via Ps readback: lane (rl,c) reads 4 bf16, expands to
// f32x4, NT-stores -> each store instruction covers 4 rows x 256B contiguous
// (full 128B lines; no partial-line NT write amplification). Mask word
// prefetched one tile ahead; counted vmcnt(4); 40KB LDS, 4 blocks/CU.
__global__ __launch_bounds__(256,4) void attn_pass2_k(
    const unsigned short* __restrict__ Qp, const unsigned short* __restrict__ Kp,
    const unsigned short* __restrict__ Vt, const unsigned long long* __restrict__ mbits,
    const float* __restrict__ linv, float* __restrict__ attn,
    unsigned short* __restrict__ ctx){
  __shared__ __align__(16) char Ks[2][8192];          // 64 k x 64 dk
  __shared__ __align__(16) char Vs[2][8192];          // 64 dv x 64 k
  __shared__ __align__(16) unsigned short Ps[64*64];  // stride 64, XOR-swizzled
  const int tid = threadIdx.x;
  const int wave = tid >> 6, lane = tid & 63;
  const int lr = lane & 15, lg = lane >> 4;
  const int flat = blockIdx.x;                        // 1024 blocks
  const int wg = ((flat & 7) << 7) + (flat >> 3);     // XCD-contiguous
  const int bh = wg >> 5, b = bh >> 4, h = bh & 15;
  const int qbase = (wg & 31)*64 + wave*16;
  const f32x4 fz = {0.f,0.f,0.f,0.f};

  short8 qf[2];
#pragma unroll
  for (int ks=0;ks<2;ks++)
    qf[ks] = *(const short8*)(Qp + (size_t)(b*2048 + qbase + lr)*1024
                              + h*64 + ks*32 + lg*8);
  const int qrow = qbase + lr;
  const float li = linv[(size_t)bh*2048 + qrow];
  const unsigned long long* mrow = mbits + (((size_t)(b*2048 + qrow)) << 5);

  f32x4 oacc[4];
#pragma unroll
  for (int bj=0;bj<4;bj++) oacc[bj] = fz;

  auto stageK = [&](int t, int bu){
#pragma unroll
    for (int i=0;i<2;i++){
      int byte = i*4096 + tid*16;
      int row = byte >> 7;
      int ch  = (byte >> 4) & 7;
      gload16(Kp + (size_t)(b*2048 + t*64 + row)*1024 + h*64 + ((ch ^ (row&7))*8),
              &Ks[bu][i*4096 + wave*1024]);
    }
  };
  auto stageV = [&](int t, int bu){
#pragma unroll
    for (int i=0;i<2;i++){
      int byte = i*4096 + tid*16;
      int row = byte >> 7;
      int ch  = (byte >> 4) & 7;
      gload16(Vt + (size_t)(bh*64 + row)*2048 + t*64 + ((ch ^ (row&7))*8),
              &Vs[bu][i*4096 + wave*1024]);
    }
  };
  auto wload = [&](int t) -> unsigned long long {
    unsigned long long wv;
    const unsigned long long* ma = mrow + t;
    asm volatile("global_load_dwordx2 %0, %1, off" : "=v"(wv) : "v"(ma));
    return wv;
  };

  // prologue: stage tile 0 + mask word 0, full drain, align waves
  stageK(0,0); stageV(0,0);
  unsigned long long w_cur = wload(0), w_nxt = 0;
  asm volatile("s_waitcnt vmcnt(0)" ::: "memory");
  __builtin_amdgcn_s_barrier();

  char* psb = (char*)Ps;
  const int prow = (wave*16 + lr);                 // Ps row for this lane
  const int pswz = (lr & 7) << 4;                  // XOR byte swizzle (write)
  const int rl = lane >> 4, c = lane & 15;         // readback lane roles
  float* attnW = attn + ((size_t)bh*2048 + qbase)*2048 + c*4;
  int buf = 0;
  for (int t=0; t<32; ++t){
    // issue next tile's gloads + mask word FIRST (all older than stores)
    if (t+1 < 32){ stageK(t+1, buf^1); stageV(t+1, buf^1); w_nxt = wload(t+1); }
    __builtin_amdgcn_sched_barrier(0);

    f32x4 s2[4];
#pragma unroll
    for (int bj=0;bj<4;bj++) s2[bj] = fz;
#pragma unroll
    for (int ks=0;ks<2;ks++){
      short8 kf[4];
#pragma unroll
      for (int bj=0;bj<4;bj++){
        int row = bj*16 + lr;
        kf[bj] = *(const short8*)(&Ks[buf][row*128 + (((ks*4+lg) ^ (row&7))*16)]);
      }
#pragma unroll
      for (int bj=0;bj<4;bj++)
        s2[bj] = MFMA_BF16(kf[bj], qf[ks], s2[bj]);   // swapped
    }
    // softmax -> Ps (bf16, swizzled); w_cur completed last tile
    unsigned long long w2 = w_cur >> (lg*4);
#pragma unroll
    for (int bj=0;bj<4;bj++){
      unsigned ub = (unsigned)(w2 >> (bj*16));
      f32x4 po;
#pragma unroll
      for (int r=0;r<4;r++){
        float e = __expf(s2[bj][r]*0.125f);
        po[r] = (ub & (1u<<r)) ? e*li : 0.f;
      }
      uint2 pk;
      pk.x = cvt_pk_bf16(po[0], po[1]);
      pk.y = cvt_pk_bf16(po[2], po[3]);
      *reinterpret_cast<uint2*>(psb + prow*128 + (((bj*32 + lg*8) ^ pswz))) = pk;
    }
    // Ps visible to this wave (wave-private rows) -> full-line NT stores
    __builtin_amdgcn_sched_barrier(0);
    asm volatile("s_waitcnt lgkmcnt(0)" ::: "memory");
    __builtin_amdgcn_sched_barrier(0);
#pragma unroll
    for (int rg=0; rg<4; ++rg){
      int R = rg*4 + rl;                           // row 0..15 within wave
      const char* src = psb + (wave*16 + R)*128 + ((c*8) ^ ((R&7)<<4));
      uint2 d = *reinterpret_cast<const uint2*>(src);
      union { unsigned u; float f; } c0, c1, c2, c3;
      c0.u = d.x << 16; c1.u = d.x & 0xffff0000u;
      c2.u = d.y << 16; c3.u = d.y & 0xffff0000u;
      f32x4 po2 = { c0.f, c1.f, c2.f, c3.f };
      __builtin_nontemporal_store(po2,
          reinterpret_cast<f32x4*>(attnW + (size_t)R*2048 + t*64));
    }
    // PV: O(16q x 64dv) += P(16q x 64k) @ V(64k x 64dv)
#pragma unroll
    for (int ks=0;ks<2;ks++){
      short8 pa = *(const short8*)(psb + prow*128 + (((ks*64 + lg*16) ^ pswz)));
      short8 vf[4];
#pragma unroll
      for (int bj=0;bj<4;bj++){
        int row = bj*16 + lr;
        vf[bj] = *(const short8*)(&Vs[buf][row*128 + (((ks*4+lg) ^ (row&7))*16)]);
      }
#pragma unroll
      for (int bj=0;bj<4;bj++)
        oacc[bj] = MFMA_BF16(pa, vf[bj], oacc[bj]);
    }
    // counted drain: completes {4 gloads, 1 wload}, leaves 4 NT stores.
    if (t+1 < 32){
      __builtin_amdgcn_sched_barrier(0);
      asm volatile("s_waitcnt vmcnt(4)" ::: "memory");
      asm volatile("s_waitcnt lgkmcnt(0)" ::: "memory");
      __builtin_amdgcn_s_barrier();
    }
    w_cur = w_nxt;
    buf ^= 1;
  }
  // ctx write: q = qbase + lg*4 + r, dv = bj*16 + lr
#pragma unroll
  for (int bj=0;bj<4;bj++)
#pragma unroll
    for (int r=0;r<4;r++){
      int qr2 = qbase + lg*4 + r;
      int dv = bj*16 + lr;
      ctx[(size_t)(b*2048 + qr2)*1024 + h*64 + dv] = f2bf(oacc[bj][r]);
    }
}

// --------------------------------------------------- out-proj (BM=64) ------
__global__ __launch_bounds__(256,4) void gemm_out_k(const unsigned short* __restrict__ A,
    const unsigned short* __restrict__ W, float* __restrict__ out,
    const float* __restrict__ bias){
  __shared__ __align__(16) char As[2][4096];
  __shared__ __align__(16) char Bs[2][8192];
  const int tid = threadIdx.x;
  const int wave = tid >> 6, lane = tid & 63;
  const int lr = lane & 15, lg = lane >> 4;
  const int m0 = blockIdx.y * 64, n0 = blockIdx.x * 128;
  const int wr = wave >> 1, wc = wave & 1;
  const f32x4 fz = {0.f,0.f,0.f,0.f};

  f32x4 acc[2][4];
#pragma unroll
  for (int i=0;i<2;i++)
#pragma unroll
    for (int j=0;j<4;j++) acc[i][j] = fz;

  auto stage = [&](int kt, int bu){
    int kof = kt*32 + (tid&3)*8;
    gload16(A + (size_t)(m0 + (tid>>2))*1024 + kof, &As[bu][wave*1024]);
#pragma unroll
    for (int i=0;i<2;i++){
      int row = i*64 + (tid>>2);
      gload16(W + (size_t)(n0+row)*1024 + kof, &Bs[bu][i*4096 + wave*1024]);
    }
  };
  stage(0,0);
  int buf = 0;
  for (int kt=0; kt<32; ++kt){
    __syncthreads();
    if (kt+1 < 32) stage(kt+1, buf^1);
    short8 af[2], bf[4];
#pragma unroll
    for (int i=0;i<2;i++) af[i] = *(const short8*)(&As[buf][(wr*32+i*16+lr)*64 + lg*16]);
#pragma unroll
    for (int j=0;j<4;j++) bf[j] = *(const short8*)(&Bs[buf][(wc*64+j*16+lr)*64 + lg*16]);
#pragma unroll
    for (int i=0;i<2;i++)
#pragma unroll
      for (int j=0;j<4;j++)
        acc[i][j] = MFMA_BF16(af[i], bf[j], acc[i][j]);
    buf ^= 1;
  }
#pragma unroll
  for (int i=0;i<2;i++)
#pragma unroll
    for (int j=0;j<4;j++){
      int n = n0 + wc*64 + j*16 + lr;
      float bv = bias[n];
#pragma unroll
      for (int r=0;r<4;r++){
        int m = m0 + wr*32 + i*16 + lg*4 + r;
        out[(size_t)m*1024 + n] = acc[i][j][r] + bv;
      }
    }
}

// ------------------------------------------------------------------ host ---
extern "C" void kernel_launch(void* const* d_in, const int* in_sizes, int n_in,
                              void* d_out, int out_size, void* d_ws, size_t ws_size,
                              hipStream_t stream){
  (void)in_sizes; (void)n_in; (void)out_size;
  const float* q   = (const float*)d_in[0];
  const float* k   = (const float*)d_in[1];
  const float* v   = (const float*)d_in[2];
  const int*  mask = (const int*)d_in[3];
  const float* wq  = (const float*)d_in[4];
  const float* wk  = (const float*)d_in[5];
  const float* wv  = (const float*)d_in[6];
  const float* wo  = (const float*)d_in[7];
  const float* wob = (const float*)d_in[8];

  char* ws = (char*)d_ws;
  const size_t MB = 1ull << 20;
  unsigned short* qhi = (unsigned short*)(ws +  0*MB);
  unsigned short* qlo = (unsigned short*)(ws +  8*MB);
  unsigned short* khi = (unsigned short*)(ws + 16*MB);
  unsigned short* klo = (unsigned short*)(ws + 24*MB);
  unsigned short* vb  = (unsigned short*)(ws + 32*MB);
  unsigned short* wqh = (unsigned short*)(ws + 40*MB);
  unsigned short* wql = (unsigned short*)(ws + 42*MB);
  unsigned short* wkh = (unsigned short*)(ws + 44*MB);
  unsigned short* wkl = (unsigned short*)(ws + 46*MB);
  unsigned short* wvb = (unsigned short*)(ws + 48*MB);
  unsigned short* wob_= (unsigned short*)(ws + 50*MB);   // 2 MB: [50,52)
  unsigned short* Qp  = (unsigned short*)(ws + 52*MB);
  unsigned short* Kp  = (unsigned short*)(ws + 60*MB);
  unsigned short* Vt  = (unsigned short*)(ws + 68*MB);
  unsigned short* Ctx = (unsigned short*)(ws + 76*MB);
  unsigned long long* mbits = (unsigned long long*)(ws + 84*MB);
  // lin (256 KB) reuses the qhi region: qhi is dead after proj_qkv_k.
  float*          lin = (float*)(ws + 0*MB);
  if (ws_size < 85*MB) return;   // need 85 MB scratch

  float* ctx_out  = (float*)d_out;
  float* attn_out = ctx_out + (size_t)2*2048*1024;

  prep_k<<<24576,256,0,stream>>>(q,k,v,mask,wq,wk,wv,wo,
                                 qhi,qlo,khi,klo,vb,
                                 wqh,wql,wkh,wkl,wvb,wob_, mbits);

  proj_qkv_k<<<dim3(8,32,3),256,0,stream>>>(qhi,qlo,khi,klo,vb,
                                            wqh,wql,wkh,wkl,wvb, Qp,Kp,Vt);

  attn_pass1_k<<<512,256,0,stream>>>(Qp, Kp, mbits, lin);
  attn_pass2_k<<<1024,256,0,stream>>>(Qp, Kp, Vt, mbits, lin,
                                      attn_out, Ctx);

  gemm_out_k<<<dim3(8,64),256,0,stream>>>(Ctx, wob_, ctx_out, wob);
}